// Round 13
// baseline (1771.269 us; speedup 1.0000x reference)
//
#include <hip/hip_runtime.h>
#include <hip/hip_bf16.h>
#include <stdint.h>

typedef __attribute__((ext_vector_type(4))) float f32x4;
typedef __attribute__((ext_vector_type(2))) float f32x2;
typedef __attribute__((ext_vector_type(8))) short s16x8;
typedef __attribute__((ext_vector_type(4))) uint32_t u32x4;
typedef __hip_bfloat16 bf16;
typedef unsigned long long u64;

__device__ __forceinline__ float sigf(float x){ return 1.f/(1.f+__expf(-x)); }
__device__ __forceinline__ float tanh_f(float x){ float e=__expf(2.f*x); return (e-1.f)/(e+1.f); }

__device__ __forceinline__ u64 ld_u64_agent(const u64* p){
  return __hip_atomic_load(p, __ATOMIC_RELAXED, __HIP_MEMORY_SCOPE_AGENT);
}
__device__ __forceinline__ void st_u64_agent(u64* p, u64 v){
  __hip_atomic_store(p, v, __ATOMIC_RELAXED, __HIP_MEMORY_SCOPE_AGENT);
}

// async global -> LDS, 16B per lane. LDS dest = wave-uniform base + lane*16.
__device__ __forceinline__ void gload_lds16(const void* g, void* l){
  __builtin_amdgcn_global_load_lds(
      (const __attribute__((address_space(1))) uint32_t*)g,
      (__attribute__((address_space(3))) uint32_t*)l, 16, 0, 0);
}

// ---------------- convert f32 -> bf16 ----------------
__global__ __launch_bounds__(256) void k_convert(const float* __restrict__ in, bf16* __restrict__ outp, int n){
  int i = (blockIdx.x*256 + threadIdx.x)*4;
  if (i >= n) return;
  f32x4 v = *(const f32x4*)&in[i];
  alignas(8) bf16 tmp[4] = {__float2bfloat16(v.x), __float2bfloat16(v.y), __float2bfloat16(v.z), __float2bfloat16(v.w)};
  *(uint64_t*)&outp[i] = *(const uint64_t*)tmp;
}

// ---------------- encoder embedding gather -> Xe[t*16+b][e] (bf16) ----------------
__global__ __launch_bounds__(256) void k_embed(const int* __restrict__ enc_in, const float* __restrict__ emb,
                                               bf16* __restrict__ Xe){
  int i = blockIdx.x*256 + threadIdx.x;
  int o = i*4;
  int row = o >> 9, e = o & 511;
  int t = row >> 4, b = row & 15;
  int tok = enc_in[b*512 + t];
  f32x4 v = *(const f32x4*)&emb[(size_t)tok*512 + e];
  alignas(8) bf16 tmp[4] = {__float2bfloat16(v.x), __float2bfloat16(v.y), __float2bfloat16(v.z), __float2bfloat16(v.w)};
  *(uint64_t*)&Xe[o] = *(const uint64_t*)tmp;
}

// ---------------- bf16 MFMA GEMM: C[M][N] = A[M][K] * B[N][K]^T + bias ----------------
// 128x128 tile, BK=32, gload_lds width-16 staging, supertile launch remap.
template<int OUT_BF16>
__global__ __launch_bounds__(256) void k_gemm(
    const bf16* __restrict__ A, const bf16* __restrict__ Bm,
    const float* __restrict__ bias1, const float* __restrict__ bias2,
    void* __restrict__ Cp, int M, int N, int K, int MT, int SM, int SN)
{
  __shared__ bf16 Al[128*32];
  __shared__ bf16 Bl[128*32];
  const int tid = threadIdx.x;
  int bid = blockIdx.x;
  int ss  = SM*SN;
  int sid = bid / ss, lid = bid % ss;
  int nsm = MT / SM;
  int mg = sid % nsm, ng = sid / nsm;
  int mt = mg*SM + lid/SN, nt = ng*SN + lid%SN;
  const int n0 = nt*128, m0 = mt*128;

  const int wv = tid >> 6, lane = tid & 63;
  const int wr = (wv >> 1)*64, wc = (wv & 1)*64;
  const int lrow = lane & 15, lk = (lane >> 4)*8;
  const int r1 = tid >> 2, kq = (tid & 3)*8;

  f32x4 acc[4][4];
  #pragma unroll
  for (int i=0;i<4;++i)
    #pragma unroll
    for (int j=0;j<4;++j) { f32x4 z = {0.f,0.f,0.f,0.f}; acc[i][j] = z; }

  const bf16* pa0 = &A[(size_t)(m0 + r1)*K + kq];
  const bf16* pa1 = &A[(size_t)(m0 + 64 + r1)*K + kq];
  const bf16* pb0 = &Bm[(size_t)(n0 + r1)*K + kq];
  const bf16* pb1 = &Bm[(size_t)(n0 + 64 + r1)*K + kq];

  char* AlB = (char*)Al + wv*1024;
  char* BlB = (char*)Bl + wv*1024;

  const int nk = K >> 5;
  for (int kt = 0; kt < nk; ++kt) {
    __syncthreads();                 // previous tile fully consumed
    int off = kt*32;
    gload_lds16(pa0 + off, AlB);
    gload_lds16(pa1 + off, AlB + 4096);
    gload_lds16(pb0 + off, BlB);
    gload_lds16(pb1 + off, BlB + 4096);
    __syncthreads();                 // compiler drains vmcnt before barrier
    s16x8 af[4], bfr[4];
    #pragma unroll
    for (int mi=0;mi<4;++mi) af[mi]  = *(const s16x8*)&Al[(wr + mi*16 + lrow)*32 + lk];
    #pragma unroll
    for (int ni=0;ni<4;++ni) bfr[ni] = *(const s16x8*)&Bl[(wc + ni*16 + lrow)*32 + lk];
    #pragma unroll
    for (int mi=0;mi<4;++mi)
      #pragma unroll
      for (int ni=0;ni<4;++ni)
        acc[mi][ni] = __builtin_amdgcn_mfma_f32_16x16x32_bf16(af[mi], bfr[ni], acc[mi][ni], 0, 0, 0);
  }
  const int crow = (lane >> 4)*4;
  #pragma unroll
  for (int mi=0;mi<4;++mi) {
    #pragma unroll
    for (int ni=0;ni<4;++ni) {
      int cc = n0 + wc + ni*16 + lrow;
      float badd = (bias1 ? bias1[cc] : 0.f) + (bias2 ? bias2[cc] : 0.f);
      #pragma unroll
      for (int q=0;q<4;++q) {
        int rr = m0 + wr + mi*16 + crow + q;
        float v = acc[mi][ni][q] + badd;
        if (OUT_BF16) ((bf16*)Cp)[(size_t)rr*N + cc] = __float2bfloat16(v);
        else          ((float*)Cp)[(size_t)rr*N + cc] = v;
      }
    }
  }
}

// ============ per-batch recurrence groups (R8 proven structure) ============

// ---------------- encoder recurrence ----------------
__global__ __launch_bounds__(512, 1) void k_enc_r(
    const bf16* __restrict__ GXe, const float* __restrict__ w_hh,
    u64* __restrict__ hex, float* __restrict__ cT, float* __restrict__ hT,
    float* __restrict__ enc_out)
{
  const int tid = threadIdx.x, bid = blockIdx.x;
  const int b = bid >> 4, r = bid & 15;
  const int ksl = tid & 15, c = tid >> 4;

  __shared__ float h_lds[512];
  __shared__ float gate_lds[128];

  f32x4 wreg[4][8];
  #pragma unroll
  for (int cc = 0; cc < 4; ++cc) {
    int ic = c*4 + cc;
    int gc = (ic >> 5)*512 + r*32 + (ic & 31);
    const float* wrow = &w_hh[(size_t)gc*512 + ksl*32];
    #pragma unroll
    for (int i = 0; i < 8; ++i) wreg[cc][i] = *(const f32x4*)&wrow[((i + ksl) & 7)*4];
  }
  const int gc0 = ((c*4) >> 5)*512 + r*32 + ((c*4) & 31);
  u64* hb = hex + (size_t)b*1024;
  float c_reg = 0.f;
  const int jg = r*32 + tid;   // producer's j (tid<32)

  for (int t = 0; t < 512; ++t) {
    uint64_t gx = 0;
    if (ksl == 0) gx = *(const uint64_t*)&GXe[(size_t)(t*16 + b)*2048 + gc0];
    float a0=0.f, a1=0.f, a2=0.f, a3=0.f;
    if (t > 0) {
      const uint32_t tg = (uint32_t)t;
      u64* slot = &hb[(t & 1)*512 + tid];
      u64 v = ld_u64_agent(slot);
      uint32_t spins = 0;
      while ((uint32_t)(v >> 32) != tg) {
        v = ld_u64_agent(slot);
        if (++spins > (1u<<18)) break;      // broken protocol -> bounded, visible failure
      }
      h_lds[tid] = __uint_as_float((uint32_t)v);
      __syncthreads();                       // (B)
      const float* hrow = &h_lds[ksl*32];
      #pragma unroll
      for (int i = 0; i < 8; ++i) {
        f32x4 hv = *(const f32x4*)&hrow[((i + ksl) & 7)*4];
        a0 = __fmaf_rn(hv.x, wreg[0][i].x, a0); a0 = __fmaf_rn(hv.y, wreg[0][i].y, a0);
        a0 = __fmaf_rn(hv.z, wreg[0][i].z, a0); a0 = __fmaf_rn(hv.w, wreg[0][i].w, a0);
        a1 = __fmaf_rn(hv.x, wreg[1][i].x, a1); a1 = __fmaf_rn(hv.y, wreg[1][i].y, a1);
        a1 = __fmaf_rn(hv.z, wreg[1][i].z, a1); a1 = __fmaf_rn(hv.w, wreg[1][i].w, a1);
        a2 = __fmaf_rn(hv.x, wreg[2][i].x, a2); a2 = __fmaf_rn(hv.y, wreg[2][i].y, a2);
        a2 = __fmaf_rn(hv.z, wreg[2][i].z, a2); a2 = __fmaf_rn(hv.w, wreg[2][i].w, a2);
        a3 = __fmaf_rn(hv.x, wreg[3][i].x, a3); a3 = __fmaf_rn(hv.y, wreg[3][i].y, a3);
        a3 = __fmaf_rn(hv.z, wreg[3][i].z, a3); a3 = __fmaf_rn(hv.w, wreg[3][i].w, a3);
      }
      #pragma unroll
      for (int s = 1; s < 16; s <<= 1) {
        a0 += __shfl_xor(a0, s); a1 += __shfl_xor(a1, s);
        a2 += __shfl_xor(a2, s); a3 += __shfl_xor(a3, s);
      }
    }
    if (ksl == 0) {
      gate_lds[c*4 + 0] = a0 + __uint_as_float((uint32_t)(gx & 0xffffu) << 16);
      gate_lds[c*4 + 1] = a1 + __uint_as_float((uint32_t)((gx >> 16) & 0xffffu) << 16);
      gate_lds[c*4 + 2] = a2 + __uint_as_float((uint32_t)((gx >> 32) & 0xffffu) << 16);
      gate_lds[c*4 + 3] = a3 + __uint_as_float((uint32_t)((gx >> 48) & 0xffffu) << 16);
    }
    __syncthreads();                          // (D)
    if (tid < 32) {
      float gi = gate_lds[tid];
      float gf = gate_lds[32 + tid];
      float gg = gate_lds[64 + tid];
      float go = gate_lds[96 + tid];
      float cn = sigf(gf)*c_reg + sigf(gi)*tanh_f(gg);
      float hn = sigf(go)*tanh_f(cn);
      c_reg = cn;
      st_u64_agent(&hb[((t+1) & 1)*512 + jg],
                   ((u64)(uint32_t)(t + 1) << 32) | (u64)__float_as_uint(hn));
      enc_out[((size_t)b*512 + t)*512 + jg] = hn;
      if (t == 511) { hT[b*512 + jg] = hn; cT[b*512 + jg] = c_reg; }
    }
  }
}

// ---------------- gates for decoder step 0 ----------------
__global__ __launch_bounds__(128) void k_gates0(
    const int* __restrict__ dec_in, const float* __restrict__ emb,
    const float* __restrict__ hT,
    const float* __restrict__ w_ih, const float* __restrict__ w_hh,
    const float* __restrict__ b_ih, const float* __restrict__ b_hh,
    float* __restrict__ g0)
{
  int gt = blockIdx.x*128 + threadIdx.x;
  int b = gt & 15, col = gt >> 4;
  const float* x0 = &emb[(size_t)dec_in[b*128] * 512];
  const float* hp = &hT[b*512];
  const float* wi = &w_ih[(size_t)col*512];
  const float* wh = &w_hh[(size_t)col*512];
  float s0=0.f, s1=0.f;
  for (int k = 0; k < 512; k += 4) {
    f32x4 xv = *(const f32x4*)&x0[k]; f32x4 wv = *(const f32x4*)&wi[k];
    f32x4 hv = *(const f32x4*)&hp[k]; f32x4 w2 = *(const f32x4*)&wh[k];
    s0 += xv.x*wv.x + xv.y*wv.y + xv.z*wv.z + xv.w*wv.w;
    s1 += hv.x*w2.x + hv.y*w2.y + hv.z*w2.z + hv.w*w2.w;
  }
  g0[b*2048 + col] = s0 + s1 + b_ih[col] + b_hh[col];
}

// ---------------- decoder recurrence (x_t == h_t for t>=1) ----------------
__global__ __launch_bounds__(512, 1) void k_dec_r(
    const float* __restrict__ w_ih, const float* __restrict__ w_hh,
    const float* __restrict__ b_ih, const float* __restrict__ b_hh,
    const float* __restrict__ gates0,
    u64* __restrict__ hex, const float* __restrict__ cT,
    float* __restrict__ dec_h, bf16* __restrict__ dec_out)
{
  const int tid = threadIdx.x, bid = blockIdx.x;
  const int b = bid >> 4, r = bid & 15;
  const int ksl = tid & 15, c = tid >> 4;

  __shared__ float h_lds[512];
  __shared__ float gate_lds[128];

  f32x4 wreg[4][8];
  float bias_c[4];
  #pragma unroll
  for (int cc = 0; cc < 4; ++cc) {
    int ic = c*4 + cc;
    int gc = (ic >> 5)*512 + r*32 + (ic & 31);
    bias_c[cc] = b_ih[gc] + b_hh[gc];
    const float* wra = &w_ih[(size_t)gc*512 + ksl*32];
    const float* wrb = &w_hh[(size_t)gc*512 + ksl*32];
    #pragma unroll
    for (int i = 0; i < 8; ++i) {
      int o = ((i + ksl) & 7)*4;
      f32x4 wa = *(const f32x4*)&wra[o];
      f32x4 wb = *(const f32x4*)&wrb[o];
      wreg[cc][i] = wa + wb;
    }
  }
  const int gc0 = ((c*4) >> 5)*512 + r*32 + ((c*4) & 31);
  u64* hb = hex + (size_t)b*1024;
  const int jg = r*32 + tid;
  float c_reg = 0.f;
  if (tid < 32) c_reg = cT[b*512 + jg];

  for (int t = 0; t < 128; ++t) {
    float a0=0.f, a1=0.f, a2=0.f, a3=0.f;
    if (t > 0) {
      const uint32_t tg = (uint32_t)t;
      u64* slot = &hb[(t & 1)*512 + tid];
      u64 v = ld_u64_agent(slot);
      uint32_t spins = 0;
      while ((uint32_t)(v >> 32) != tg) {
        v = ld_u64_agent(slot);
        if (++spins > (1u<<18)) break;
      }
      h_lds[tid] = __uint_as_float((uint32_t)v);
      __syncthreads();                       // (B)
      const float* hrow = &h_lds[ksl*32];
      #pragma unroll
      for (int i = 0; i < 8; ++i) {
        f32x4 hv = *(const f32x4*)&hrow[((i + ksl) & 7)*4];
        a0 = __fmaf_rn(hv.x, wreg[0][i].x, a0); a0 = __fmaf_rn(hv.y, wreg[0][i].y, a0);
        a0 = __fmaf_rn(hv.z, wreg[0][i].z, a0); a0 = __fmaf_rn(hv.w, wreg[0][i].w, a0);
        a1 = __fmaf_rn(hv.x, wreg[1][i].x, a1); a1 = __fmaf_rn(hv.y, wreg[1][i].y, a1);
        a1 = __fmaf_rn(hv.z, wreg[1][i].z, a1); a1 = __fmaf_rn(hv.w, wreg[1][i].w, a1);
        a2 = __fmaf_rn(hv.x, wreg[2][i].x, a2); a2 = __fmaf_rn(hv.y, wreg[2][i].y, a2);
        a2 = __fmaf_rn(hv.z, wreg[2][i].z, a2); a2 = __fmaf_rn(hv.w, wreg[2][i].w, a2);
        a3 = __fmaf_rn(hv.x, wreg[3][i].x, a3); a3 = __fmaf_rn(hv.y, wreg[3][i].y, a3);
        a3 = __fmaf_rn(hv.z, wreg[3][i].z, a3); a3 = __fmaf_rn(hv.w, wreg[3][i].w, a3);
      }
      #pragma unroll
      for (int s = 1; s < 16; s <<= 1) {
        a0 += __shfl_xor(a0, s); a1 += __shfl_xor(a1, s);
        a2 += __shfl_xor(a2, s); a3 += __shfl_xor(a3, s);
      }
    }
    if (ksl == 0) {
      if (t == 0) {
        f32x4 gv = *(const f32x4*)&gates0[(size_t)b*2048 + gc0];
        gate_lds[c*4 + 0] = gv.x; gate_lds[c*4 + 1] = gv.y;
        gate_lds[c*4 + 2] = gv.z; gate_lds[c*4 + 3] = gv.w;
      } else {
        gate_lds[c*4 + 0] = a0 + bias_c[0];
        gate_lds[c*4 + 1] = a1 + bias_c[1];
        gate_lds[c*4 + 2] = a2 + bias_c[2];
        gate_lds[c*4 + 3] = a3 + bias_c[3];
      }
    }
    __syncthreads();                          // (D)
    if (tid < 32) {
      float gi = gate_lds[tid];
      float gf = gate_lds[32 + tid];
      float gg = gate_lds[64 + tid];
      float go = gate_lds[96 + tid];
      float cn = sigf(gf)*c_reg + sigf(gi)*tanh_f(gg);
      float hn = sigf(go)*tanh_f(cn);
      c_reg = cn;
      st_u64_agent(&hb[((t+1) & 1)*512 + jg],
                   ((u64)(uint32_t)(t + 1) << 32) | (u64)__float_as_uint(hn));
      dec_h[((size_t)t*16 + b)*512 + jg] = hn;
      dec_out[((size_t)(b*128 + t))*1024 + jg] = __float2bfloat16(hn);
    }
  }
}

// ---------------- batched attention: 256 blocks = 16 b x 16 t-groups(8 t) ----------------
__global__ __launch_bounds__(256) void k_attn(
    const float* __restrict__ dec_h, const float* __restrict__ enc_out,
    bf16* __restrict__ dOut)
{
  const int tid = threadIdx.x, bid = blockIdx.x;
  const int b = bid >> 4, t0 = (bid & 15)*8;
  __shared__ float h16[8*512];
  __shared__ float sc[8*512];
  #pragma unroll
  for (int q = 0; q < 4; ++q) {
    int fi = q*256 + tid;
    int tt = fi >> 7, e4 = (fi & 127)*4;
    *(f32x4*)&h16[tt*512 + e4] = *(const f32x4*)&dec_h[((size_t)(t0 + tt)*16 + b)*512 + e4];
  }
  __syncthreads();
  const float* encb = &enc_out[(size_t)b*512*512];
  for (int si = 0; si < 2; ++si) {
    int s = si*256 + tid;
    float a[8];
    #pragma unroll
    for (int tt=0;tt<8;++tt) a[tt]=0.f;
    #pragma unroll 4
    for (int e4 = 0; e4 < 512; e4 += 4) {
      f32x4 ev = *(const f32x4*)&encb[(size_t)s*512 + e4];
      #pragma unroll
      for (int tt = 0; tt < 8; ++tt) {
        f32x4 hv = *(const f32x4*)&h16[tt*512 + e4];
        a[tt] += ev.x*hv.x + ev.y*hv.y + ev.z*hv.z + ev.w*hv.w;
      }
    }
    #pragma unroll
    for (int tt=0;tt<8;++tt) sc[tt*512 + s] = a[tt];
  }
  __syncthreads();
  {
    int wv = tid >> 6, lane = tid & 63;
    #pragma unroll
    for (int u = 0; u < 2; ++u) {
      int tt = wv*2 + u;
      float x[8];
      float m = -1e30f;
      #pragma unroll
      for (int i=0;i<8;++i){ x[i] = sc[tt*512 + i*64 + lane]; m = fmaxf(m, x[i]); }
      #pragma unroll
      for (int off=1; off<64; off<<=1) m = fmaxf(m, __shfl_xor(m, off));
      float sum = 0.f;
      #pragma unroll
      for (int i=0;i<8;++i){ x[i] = __expf(x[i]-m); sum += x[i]; }
      #pragma unroll
      for (int off=1; off<64; off<<=1) sum += __shfl_xor(sum, off);
      float inv = 1.f/sum;
      #pragma unroll
      for (int i=0;i<8;++i) sc[tt*512 + i*64 + lane] = x[i]*inv;
    }
  }
  __syncthreads();
  {
    int e0 = tid*2;
    float cx[8], cy[8];
    #pragma unroll
    for (int tt=0;tt<8;++tt){ cx[tt]=0.f; cy[tt]=0.f; }
    #pragma unroll 8
    for (int s = 0; s < 512; ++s) {
      f32x2 ev = *(const f32x2*)&encb[(size_t)s*512 + e0];
      #pragma unroll
      for (int tt = 0; tt < 8; ++tt) {
        float aw = sc[tt*512 + s];
        cx[tt] += aw*ev.x; cy[tt] += aw*ev.y;
      }
    }
    #pragma unroll
    for (int tt = 0; tt < 8; ++tt) {
      size_t rowo = ((size_t)(b*128 + t0 + tt))*1024 + 512 + e0;
      alignas(4) bf16 tmp[2] = {__float2bfloat16(cx[tt]), __float2bfloat16(cy[tt])};
      *(uint32_t*)&dOut[rowo] = *(const uint32_t*)tmp;
    }
  }
}

// ---------------- host ----------------
extern "C" void kernel_launch(void* const* d_in, const int* in_sizes, int n_in,
                              void* d_out, int out_size, void* d_ws, size_t ws_size,
                              hipStream_t stream)
{
  const int*   enc_in = (const int*)d_in[0];
  const int*   dec_in = (const int*)d_in[1];
  const float* emb    = (const float*)d_in[2];
  const float* w_ih_e = (const float*)d_in[3];
  const float* w_hh_e = (const float*)d_in[4];
  const float* b_ih_e = (const float*)d_in[5];
  const float* b_hh_e = (const float*)d_in[6];
  const float* w_ih_d = (const float*)d_in[7];
  const float* w_hh_d = (const float*)d_in[8];
  const float* b_ih_d = (const float*)d_in[9];
  const float* b_hh_d = (const float*)d_in[10];
  const float* w_proj = (const float*)d_in[11];
  const float* b_proj = (const float*)d_in[12];
  float* out = (float*)d_out;

  char* ws = (char*)d_ws;
  size_t off = 0;
  auto alloc = [&](size_t bytes)->void* { void* p = ws + off; off += (bytes + 255) & ~(size_t)255; return p; };
  bf16*  Wp      = (bf16*)alloc(32000ull*1024*2);
  bf16*  Xe      = (bf16*)alloc(8192ull*512*2);
  bf16*  Wie     = (bf16*)alloc(2048ull*512*2);
  bf16*  GXe     = (bf16*)alloc(8192ull*2048*2);
  float* enc_out = (float*)alloc(16ull*512*512*4);
  float* dec_h   = (float*)alloc(128ull*16*512*4);
  bf16*  dOutB   = (bf16*)alloc(2048ull*1024*2);
  u64*   hexE    = (u64*)alloc(16ull*1024*8);    // [16 groups][2][512] tagged u64
  u64*   hexD    = (u64*)alloc(16ull*1024*8);
  float* cT      = (float*)alloc(16*512*4);
  float* hT      = (float*)alloc(16*512*4);
  float* g0      = (float*)alloc(16*2048*4);
  if (off > ws_size) return;  // workspace too small -> fail validation loudly

  // zero tags in both exchange arenas (contiguous) each call
  (void)hipMemsetAsync(hexE, 0, 16ull*1024*8*2, stream);

  k_convert<<<32000, 256, 0, stream>>>(w_proj, Wp, 32768000);
  k_convert<<<1024, 256, 0, stream>>>(w_ih_e, Wie, 1048576);
  k_embed<<<4096, 256, 0, stream>>>(enc_in, emb, Xe);
  // encoder input gates: GXe = Xe @ w_ih_e^T + (b_ih_e + b_hh_e)
  k_gemm<1><<<1024, 256, 0, stream>>>(Xe, Wie, b_ih_e, b_hh_e, GXe, 8192, 2048, 512, 64, 4, 4);
  // 16 independent per-batch recurrence groups x 16 blocks
  k_enc_r<<<256, 512, 0, stream>>>(GXe, w_hh_e, hexE, cT, hT, enc_out);
  k_gates0<<<256, 128, 0, stream>>>(dec_in, emb, hT, w_ih_d, w_hh_d, b_ih_d, b_hh_d, g0);
  k_dec_r<<<256, 512, 0, stream>>>(w_ih_d, w_hh_d, b_ih_d, b_hh_d, g0, hexD, cT, dec_h, dOutB);
  k_attn<<<256, 256, 0, stream>>>(dec_h, enc_out, dOutB);
  // logits = dec_out @ w_proj^T + b_proj
  k_gemm<0><<<4000, 256, 0, stream>>>(dOutB, Wp, b_proj, nullptr, out, 2048, 32000, 1024, 16, 4, 5);
}

// Round 14
// 1731.396 us; speedup vs baseline: 1.0230x; 1.0230x over previous
//
#include <hip/hip_runtime.h>
#include <hip/hip_bf16.h>
#include <stdint.h>

typedef __attribute__((ext_vector_type(4))) float f32x4;
typedef __attribute__((ext_vector_type(2))) float f32x2;
typedef __attribute__((ext_vector_type(8))) short s16x8;
typedef __attribute__((ext_vector_type(4))) uint32_t u32x4;
typedef __hip_bfloat16 bf16;
typedef unsigned long long u64;

__device__ __forceinline__ float sigf(float x){ return 1.f/(1.f+__expf(-x)); }
__device__ __forceinline__ float tanh_f(float x){ float e=__expf(2.f*x); return (e-1.f)/(e+1.f); }

__device__ __forceinline__ u64 ld_u64_agent(const u64* p){
  return __hip_atomic_load(p, __ATOMIC_RELAXED, __HIP_MEMORY_SCOPE_AGENT);
}
__device__ __forceinline__ void st_u64_agent(u64* p, u64 v){
  __hip_atomic_store(p, v, __ATOMIC_RELAXED, __HIP_MEMORY_SCOPE_AGENT);
}

// async global -> LDS, 16B per lane. LDS dest = wave-uniform base + lane*16.
__device__ __forceinline__ void gload_lds16(const void* g, void* l){
  __builtin_amdgcn_global_load_lds(
      (const __attribute__((address_space(1))) uint32_t*)g,
      (__attribute__((address_space(3))) uint32_t*)l, 16, 0, 0);
}

// ---------------- convert f32 -> bf16 ----------------
__global__ __launch_bounds__(256) void k_convert(const float* __restrict__ in, bf16* __restrict__ outp, int n){
  int i = (blockIdx.x*256 + threadIdx.x)*4;
  if (i >= n) return;
  f32x4 v = *(const f32x4*)&in[i];
  alignas(8) bf16 tmp[4] = {__float2bfloat16(v.x), __float2bfloat16(v.y), __float2bfloat16(v.z), __float2bfloat16(v.w)};
  *(uint64_t*)&outp[i] = *(const uint64_t*)tmp;
}

// ---------------- encoder embedding gather -> Xe[t*16+b][e] (bf16) ----------------
__global__ __launch_bounds__(256) void k_embed(const int* __restrict__ enc_in, const float* __restrict__ emb,
                                               bf16* __restrict__ Xe){
  int i = blockIdx.x*256 + threadIdx.x;
  int o = i*4;
  int row = o >> 9, e = o & 511;
  int t = row >> 4, b = row & 15;
  int tok = enc_in[b*512 + t];
  f32x4 v = *(const f32x4*)&emb[(size_t)tok*512 + e];
  alignas(8) bf16 tmp[4] = {__float2bfloat16(v.x), __float2bfloat16(v.y), __float2bfloat16(v.z), __float2bfloat16(v.w)};
  *(uint64_t*)&Xe[o] = *(const uint64_t*)tmp;
}

// ---------------- bf16 MFMA GEMM: C[M][N] = A[M][K] * B[N][K]^T + bias ----------------
// 128x128 tile, BK=64 (halved barrier count vs BK=32), gload_lds width-16 staging.
template<int OUT_BF16>
__global__ __launch_bounds__(256) void k_gemm(
    const bf16* __restrict__ A, const bf16* __restrict__ Bm,
    const float* __restrict__ bias1, const float* __restrict__ bias2,
    void* __restrict__ Cp, int M, int N, int K)
{
  __shared__ bf16 Al[128*64];
  __shared__ bf16 Bl[128*64];
  const int tid = threadIdx.x;
  const int n0 = blockIdx.x*128, m0 = blockIdx.y*128;
  const int wv = tid >> 6, lane = tid & 63;
  const int wr = (wv >> 1)*64, wc = (wv & 1)*64;
  const int lrow = lane & 15, lk = (lane >> 4)*8;
  const int r1 = tid >> 3, kq = (tid & 7)*8;   // staging: 32 rows x 64 cols per pass

  f32x4 acc[4][4];
  #pragma unroll
  for (int i=0;i<4;++i)
    #pragma unroll
    for (int j=0;j<4;++j) { f32x4 z = {0.f,0.f,0.f,0.f}; acc[i][j] = z; }

  const bf16* pa[4];
  const bf16* pb[4];
  #pragma unroll
  for (int i=0;i<4;++i) {
    pa[i] = &A[(size_t)(m0 + i*32 + r1)*K + kq];
    pb[i] = &Bm[(size_t)(n0 + i*32 + r1)*K + kq];
  }
  char* AlB = (char*)Al + wv*1024;
  char* BlB = (char*)Bl + wv*1024;

  const int nk = K >> 6;
  for (int kt = 0; kt < nk; ++kt) {
    __syncthreads();                 // previous tile fully consumed
    int off = kt*64;
    #pragma unroll
    for (int i=0;i<4;++i) gload_lds16(pa[i] + off, AlB + i*4096);
    #pragma unroll
    for (int i=0;i<4;++i) gload_lds16(pb[i] + off, BlB + i*4096);
    __syncthreads();                 // compiler drains vmcnt before barrier
    #pragma unroll
    for (int kk = 0; kk < 2; ++kk) {
      s16x8 af[4], bfr[4];
      #pragma unroll
      for (int mi=0;mi<4;++mi) af[mi]  = *(const s16x8*)&Al[(wr + mi*16 + lrow)*64 + kk*32 + lk];
      #pragma unroll
      for (int ni=0;ni<4;++ni) bfr[ni] = *(const s16x8*)&Bl[(wc + ni*16 + lrow)*64 + kk*32 + lk];
      #pragma unroll
      for (int mi=0;mi<4;++mi)
        #pragma unroll
        for (int ni=0;ni<4;++ni)
          acc[mi][ni] = __builtin_amdgcn_mfma_f32_16x16x32_bf16(af[mi], bfr[ni], acc[mi][ni], 0, 0, 0);
    }
  }
  const int crow = (lane >> 4)*4;
  #pragma unroll
  for (int mi=0;mi<4;++mi) {
    #pragma unroll
    for (int ni=0;ni<4;++ni) {
      int cc = n0 + wc + ni*16 + lrow;
      float badd = (bias1 ? bias1[cc] : 0.f) + (bias2 ? bias2[cc] : 0.f);
      #pragma unroll
      for (int q=0;q<4;++q) {
        int rr = m0 + wr + mi*16 + crow + q;
        float v = acc[mi][ni][q] + badd;
        if (OUT_BF16) ((bf16*)Cp)[(size_t)rr*N + cc] = __float2bfloat16(v);
        else          ((float*)Cp)[(size_t)rr*N + cc] = v;
      }
    }
  }
}

// ============ per-batch recurrence groups (R8 proven structure) ============

// ---------------- encoder recurrence ----------------
__global__ __launch_bounds__(512, 1) void k_enc_r(
    const bf16* __restrict__ GXe, const float* __restrict__ w_hh,
    u64* __restrict__ hex, float* __restrict__ cT, float* __restrict__ hT,
    float* __restrict__ enc_out)
{
  const int tid = threadIdx.x, bid = blockIdx.x;
  const int b = bid >> 4, r = bid & 15;
  const int ksl = tid & 15, c = tid >> 4;

  __shared__ float h_lds[512];
  __shared__ float gate_lds[128];

  f32x4 wreg[4][8];
  #pragma unroll
  for (int cc = 0; cc < 4; ++cc) {
    int ic = c*4 + cc;
    int gc = (ic >> 5)*512 + r*32 + (ic & 31);
    const float* wrow = &w_hh[(size_t)gc*512 + ksl*32];
    #pragma unroll
    for (int i = 0; i < 8; ++i) wreg[cc][i] = *(const f32x4*)&wrow[((i + ksl) & 7)*4];
  }
  const int gc0 = ((c*4) >> 5)*512 + r*32 + ((c*4) & 31);
  u64* hb = hex + (size_t)b*1024;
  float c_reg = 0.f;
  const int jg = r*32 + tid;   // producer's j (tid<32)

  for (int t = 0; t < 512; ++t) {
    uint64_t gx = 0;
    if (ksl == 0) gx = *(const uint64_t*)&GXe[(size_t)(t*16 + b)*2048 + gc0];
    float a0=0.f, a1=0.f, a2=0.f, a3=0.f;
    if (t > 0) {
      const uint32_t tg = (uint32_t)t;
      u64* slot = &hb[(t & 1)*512 + tid];
      u64 v = ld_u64_agent(slot);
      uint32_t spins = 0;
      while ((uint32_t)(v >> 32) != tg) {
        v = ld_u64_agent(slot);
        if (++spins > (1u<<18)) break;      // broken protocol -> bounded, visible failure
      }
      h_lds[tid] = __uint_as_float((uint32_t)v);
      __syncthreads();                       // (B)
      const float* hrow = &h_lds[ksl*32];
      #pragma unroll
      for (int i = 0; i < 8; ++i) {
        f32x4 hv = *(const f32x4*)&hrow[((i + ksl) & 7)*4];
        a0 = __fmaf_rn(hv.x, wreg[0][i].x, a0); a0 = __fmaf_rn(hv.y, wreg[0][i].y, a0);
        a0 = __fmaf_rn(hv.z, wreg[0][i].z, a0); a0 = __fmaf_rn(hv.w, wreg[0][i].w, a0);
        a1 = __fmaf_rn(hv.x, wreg[1][i].x, a1); a1 = __fmaf_rn(hv.y, wreg[1][i].y, a1);
        a1 = __fmaf_rn(hv.z, wreg[1][i].z, a1); a1 = __fmaf_rn(hv.w, wreg[1][i].w, a1);
        a2 = __fmaf_rn(hv.x, wreg[2][i].x, a2); a2 = __fmaf_rn(hv.y, wreg[2][i].y, a2);
        a2 = __fmaf_rn(hv.z, wreg[2][i].z, a2); a2 = __fmaf_rn(hv.w, wreg[2][i].w, a2);
        a3 = __fmaf_rn(hv.x, wreg[3][i].x, a3); a3 = __fmaf_rn(hv.y, wreg[3][i].y, a3);
        a3 = __fmaf_rn(hv.z, wreg[3][i].z, a3); a3 = __fmaf_rn(hv.w, wreg[3][i].w, a3);
      }
      #pragma unroll
      for (int s = 1; s < 16; s <<= 1) {
        a0 += __shfl_xor(a0, s); a1 += __shfl_xor(a1, s);
        a2 += __shfl_xor(a2, s); a3 += __shfl_xor(a3, s);
      }
    }
    if (ksl == 0) {
      gate_lds[c*4 + 0] = a0 + __uint_as_float((uint32_t)(gx & 0xffffu) << 16);
      gate_lds[c*4 + 1] = a1 + __uint_as_float((uint32_t)((gx >> 16) & 0xffffu) << 16);
      gate_lds[c*4 + 2] = a2 + __uint_as_float((uint32_t)((gx >> 32) & 0xffffu) << 16);
      gate_lds[c*4 + 3] = a3 + __uint_as_float((uint32_t)((gx >> 48) & 0xffffu) << 16);
    }
    __syncthreads();                          // (D)
    if (tid < 32) {
      float gi = gate_lds[tid];
      float gf = gate_lds[32 + tid];
      float gg = gate_lds[64 + tid];
      float go = gate_lds[96 + tid];
      float cn = sigf(gf)*c_reg + sigf(gi)*tanh_f(gg);
      float hn = sigf(go)*tanh_f(cn);
      c_reg = cn;
      st_u64_agent(&hb[((t+1) & 1)*512 + jg],
                   ((u64)(uint32_t)(t + 1) << 32) | (u64)__float_as_uint(hn));
      enc_out[((size_t)b*512 + t)*512 + jg] = hn;
      if (t == 511) { hT[b*512 + jg] = hn; cT[b*512 + jg] = c_reg; }
    }
  }
}

// ---------------- gates for decoder step 0 ----------------
__global__ __launch_bounds__(128) void k_gates0(
    const int* __restrict__ dec_in, const float* __restrict__ emb,
    const float* __restrict__ hT,
    const float* __restrict__ w_ih, const float* __restrict__ w_hh,
    const float* __restrict__ b_ih, const float* __restrict__ b_hh,
    float* __restrict__ g0)
{
  int gt = blockIdx.x*128 + threadIdx.x;
  int b = gt & 15, col = gt >> 4;
  const float* x0 = &emb[(size_t)dec_in[b*128] * 512];
  const float* hp = &hT[b*512];
  const float* wi = &w_ih[(size_t)col*512];
  const float* wh = &w_hh[(size_t)col*512];
  float s0=0.f, s1=0.f;
  for (int k = 0; k < 512; k += 4) {
    f32x4 xv = *(const f32x4*)&x0[k]; f32x4 wv = *(const f32x4*)&wi[k];
    f32x4 hv = *(const f32x4*)&hp[k]; f32x4 w2 = *(const f32x4*)&wh[k];
    s0 += xv.x*wv.x + xv.y*wv.y + xv.z*wv.z + xv.w*wv.w;
    s1 += hv.x*w2.x + hv.y*w2.y + hv.z*w2.z + hv.w*w2.w;
  }
  g0[b*2048 + col] = s0 + s1 + b_ih[col] + b_hh[col];
}

// ---------------- decoder recurrence (x_t == h_t for t>=1) ----------------
__global__ __launch_bounds__(512, 1) void k_dec_r(
    const float* __restrict__ w_ih, const float* __restrict__ w_hh,
    const float* __restrict__ b_ih, const float* __restrict__ b_hh,
    const float* __restrict__ gates0,
    u64* __restrict__ hex, const float* __restrict__ cT,
    float* __restrict__ dec_h, bf16* __restrict__ dec_out)
{
  const int tid = threadIdx.x, bid = blockIdx.x;
  const int b = bid >> 4, r = bid & 15;
  const int ksl = tid & 15, c = tid >> 4;

  __shared__ float h_lds[512];
  __shared__ float gate_lds[128];

  f32x4 wreg[4][8];
  float bias_c[4];
  #pragma unroll
  for (int cc = 0; cc < 4; ++cc) {
    int ic = c*4 + cc;
    int gc = (ic >> 5)*512 + r*32 + (ic & 31);
    bias_c[cc] = b_ih[gc] + b_hh[gc];
    const float* wra = &w_ih[(size_t)gc*512 + ksl*32];
    const float* wrb = &w_hh[(size_t)gc*512 + ksl*32];
    #pragma unroll
    for (int i = 0; i < 8; ++i) {
      int o = ((i + ksl) & 7)*4;
      f32x4 wa = *(const f32x4*)&wra[o];
      f32x4 wb = *(const f32x4*)&wrb[o];
      wreg[cc][i] = wa + wb;
    }
  }
  const int gc0 = ((c*4) >> 5)*512 + r*32 + ((c*4) & 31);
  u64* hb = hex + (size_t)b*1024;
  const int jg = r*32 + tid;
  float c_reg = 0.f;
  if (tid < 32) c_reg = cT[b*512 + jg];

  for (int t = 0; t < 128; ++t) {
    float a0=0.f, a1=0.f, a2=0.f, a3=0.f;
    if (t > 0) {
      const uint32_t tg = (uint32_t)t;
      u64* slot = &hb[(t & 1)*512 + tid];
      u64 v = ld_u64_agent(slot);
      uint32_t spins = 0;
      while ((uint32_t)(v >> 32) != tg) {
        v = ld_u64_agent(slot);
        if (++spins > (1u<<18)) break;
      }
      h_lds[tid] = __uint_as_float((uint32_t)v);
      __syncthreads();                       // (B)
      const float* hrow = &h_lds[ksl*32];
      #pragma unroll
      for (int i = 0; i < 8; ++i) {
        f32x4 hv = *(const f32x4*)&hrow[((i + ksl) & 7)*4];
        a0 = __fmaf_rn(hv.x, wreg[0][i].x, a0); a0 = __fmaf_rn(hv.y, wreg[0][i].y, a0);
        a0 = __fmaf_rn(hv.z, wreg[0][i].z, a0); a0 = __fmaf_rn(hv.w, wreg[0][i].w, a0);
        a1 = __fmaf_rn(hv.x, wreg[1][i].x, a1); a1 = __fmaf_rn(hv.y, wreg[1][i].y, a1);
        a1 = __fmaf_rn(hv.z, wreg[1][i].z, a1); a1 = __fmaf_rn(hv.w, wreg[1][i].w, a1);
        a2 = __fmaf_rn(hv.x, wreg[2][i].x, a2); a2 = __fmaf_rn(hv.y, wreg[2][i].y, a2);
        a2 = __fmaf_rn(hv.z, wreg[2][i].z, a2); a2 = __fmaf_rn(hv.w, wreg[2][i].w, a2);
        a3 = __fmaf_rn(hv.x, wreg[3][i].x, a3); a3 = __fmaf_rn(hv.y, wreg[3][i].y, a3);
        a3 = __fmaf_rn(hv.z, wreg[3][i].z, a3); a3 = __fmaf_rn(hv.w, wreg[3][i].w, a3);
      }
      #pragma unroll
      for (int s = 1; s < 16; s <<= 1) {
        a0 += __shfl_xor(a0, s); a1 += __shfl_xor(a1, s);
        a2 += __shfl_xor(a2, s); a3 += __shfl_xor(a3, s);
      }
    }
    if (ksl == 0) {
      if (t == 0) {
        f32x4 gv = *(const f32x4*)&gates0[(size_t)b*2048 + gc0];
        gate_lds[c*4 + 0] = gv.x; gate_lds[c*4 + 1] = gv.y;
        gate_lds[c*4 + 2] = gv.z; gate_lds[c*4 + 3] = gv.w;
      } else {
        gate_lds[c*4 + 0] = a0 + bias_c[0];
        gate_lds[c*4 + 1] = a1 + bias_c[1];
        gate_lds[c*4 + 2] = a2 + bias_c[2];
        gate_lds[c*4 + 3] = a3 + bias_c[3];
      }
    }
    __syncthreads();                          // (D)
    if (tid < 32) {
      float gi = gate_lds[tid];
      float gf = gate_lds[32 + tid];
      float gg = gate_lds[64 + tid];
      float go = gate_lds[96 + tid];
      float cn = sigf(gf)*c_reg + sigf(gi)*tanh_f(gg);
      float hn = sigf(go)*tanh_f(cn);
      c_reg = cn;
      st_u64_agent(&hb[((t+1) & 1)*512 + jg],
                   ((u64)(uint32_t)(t + 1) << 32) | (u64)__float_as_uint(hn));
      dec_h[((size_t)t*16 + b)*512 + jg] = hn;
      dec_out[((size_t)(b*128 + t))*1024 + jg] = __float2bfloat16(hn);
    }
  }
}

// ---------------- batched attention over all (t,b) ----------------
__global__ __launch_bounds__(256) void k_attn(
    const float* __restrict__ dec_h, const float* __restrict__ enc_out,
    bf16* __restrict__ dOut)
{
  const int tid = threadIdx.x, bid = blockIdx.x;
  const int b = bid >> 3, t0 = (bid & 7)*16;
  __shared__ float h16[16*512];
  __shared__ float sc[16*512];
  #pragma unroll
  for (int q = 0; q < 8; ++q) {
    int fi = q*256 + tid;
    int tt = fi >> 7, e4 = (fi & 127)*4;
    *(f32x4*)&h16[tt*512 + e4] = *(const f32x4*)&dec_h[((size_t)(t0 + tt)*16 + b)*512 + e4];
  }
  __syncthreads();
  const float* encb = &enc_out[(size_t)b*512*512];
  for (int si = 0; si < 2; ++si) {
    int s = si*256 + tid;
    float a[16];
    #pragma unroll
    for (int tt=0;tt<16;++tt) a[tt]=0.f;
    for (int e4 = 0; e4 < 512; e4 += 4) {
      f32x4 ev = *(const f32x4*)&encb[(size_t)s*512 + e4];
      #pragma unroll
      for (int tt = 0; tt < 16; ++tt) {
        f32x4 hv = *(const f32x4*)&h16[tt*512 + e4];
        a[tt] += ev.x*hv.x + ev.y*hv.y + ev.z*hv.z + ev.w*hv.w;
      }
    }
    #pragma unroll
    for (int tt=0;tt<16;++tt) sc[tt*512 + s] = a[tt];
  }
  __syncthreads();
  {
    int wv = tid >> 6, lane = tid & 63;
    #pragma unroll
    for (int u = 0; u < 4; ++u) {
      int tt = wv*4 + u;
      float x[8];
      float m = -1e30f;
      #pragma unroll
      for (int i=0;i<8;++i){ x[i] = sc[tt*512 + i*64 + lane]; m = fmaxf(m, x[i]); }
      #pragma unroll
      for (int off=1; off<64; off<<=1) m = fmaxf(m, __shfl_xor(m, off));
      float sum = 0.f;
      #pragma unroll
      for (int i=0;i<8;++i){ x[i] = __expf(x[i]-m); sum += x[i]; }
      #pragma unroll
      for (int off=1; off<64; off<<=1) sum += __shfl_xor(sum, off);
      float inv = 1.f/sum;
      #pragma unroll
      for (int i=0;i<8;++i) sc[tt*512 + i*64 + lane] = x[i]*inv;
    }
  }
  __syncthreads();
  {
    int e0 = tid*2;
    float cx[16], cy[16];
    #pragma unroll
    for (int tt=0;tt<16;++tt){ cx[tt]=0.f; cy[tt]=0.f; }
    for (int s = 0; s < 512; ++s) {
      f32x2 ev = *(const f32x2*)&encb[(size_t)s*512 + e0];
      #pragma unroll
      for (int tt = 0; tt < 16; ++tt) {
        float aw = sc[tt*512 + s];
        cx[tt] += aw*ev.x; cy[tt] += aw*ev.y;
      }
    }
    #pragma unroll
    for (int tt = 0; tt < 16; ++tt) {
      size_t rowo = ((size_t)(b*128 + t0 + tt))*1024 + 512 + e0;
      alignas(4) bf16 tmp[2] = {__float2bfloat16(cx[tt]), __float2bfloat16(cy[tt])};
      *(uint32_t*)&dOut[rowo] = *(const uint32_t*)tmp;
    }
  }
}

// ---------------- host ----------------
extern "C" void kernel_launch(void* const* d_in, const int* in_sizes, int n_in,
                              void* d_out, int out_size, void* d_ws, size_t ws_size,
                              hipStream_t stream)
{
  const int*   enc_in = (const int*)d_in[0];
  const int*   dec_in = (const int*)d_in[1];
  const float* emb    = (const float*)d_in[2];
  const float* w_ih_e = (const float*)d_in[3];
  const float* w_hh_e = (const float*)d_in[4];
  const float* b_ih_e = (const float*)d_in[5];
  const float* b_hh_e = (const float*)d_in[6];
  const float* w_ih_d = (const float*)d_in[7];
  const float* w_hh_d = (const float*)d_in[8];
  const float* b_ih_d = (const float*)d_in[9];
  const float* b_hh_d = (const float*)d_in[10];
  const float* w_proj = (const float*)d_in[11];
  const float* b_proj = (const float*)d_in[12];
  float* out = (float*)d_out;

  char* ws = (char*)d_ws;
  size_t off = 0;
  auto alloc = [&](size_t bytes)->void* { void* p = ws + off; off += (bytes + 255) & ~(size_t)255; return p; };
  bf16*  Wp      = (bf16*)alloc(32000ull*1024*2);
  bf16*  Xe      = (bf16*)alloc(8192ull*512*2);
  bf16*  Wie     = (bf16*)alloc(2048ull*512*2);
  bf16*  GXe     = (bf16*)alloc(8192ull*2048*2);
  float* enc_out = (float*)alloc(16ull*512*512*4);
  float* dec_h   = (float*)alloc(128ull*16*512*4);
  bf16*  dOutB   = (bf16*)alloc(2048ull*1024*2);
  u64*   hexE    = (u64*)alloc(16ull*1024*8);    // [16 groups][2][512] tagged u64
  u64*   hexD    = (u64*)alloc(16ull*1024*8);
  float* cT      = (float*)alloc(16*512*4);
  float* hT      = (float*)alloc(16*512*4);
  float* g0      = (float*)alloc(16*2048*4);
  if (off > ws_size) return;  // workspace too small -> fail validation loudly

  // zero tags in both exchange arenas (contiguous) each call
  (void)hipMemsetAsync(hexE, 0, 16ull*1024*8*2, stream);

  k_convert<<<32000, 256, 0, stream>>>(w_proj, Wp, 32768000);
  k_convert<<<1024, 256, 0, stream>>>(w_ih_e, Wie, 1048576);
  k_embed<<<4096, 256, 0, stream>>>(enc_in, emb, Xe);
  // encoder input gates for all timesteps: GXe = Xe @ w_ih_e^T + (b_ih_e + b_hh_e)
  k_gemm<1><<<dim3(16, 64), 256, 0, stream>>>(Xe, Wie, b_ih_e, b_hh_e, GXe, 8192, 2048, 512);
  // 16 independent per-batch recurrence groups x 16 blocks
  k_enc_r<<<256, 512, 0, stream>>>(GXe, w_hh_e, hexE, cT, hT, enc_out);
  k_gates0<<<256, 128, 0, stream>>>(dec_in, emb, hT, w_ih_d, w_hh_d, b_ih_d, b_hh_d, g0);
  k_dec_r<<<256, 512, 0, stream>>>(w_ih_d, w_hh_d, b_ih_d, b_hh_d, g0, hexD, cT, dec_h, dOutB);
  k_attn<<<128, 256, 0, stream>>>(dec_h, enc_out, dOutB);
  // logits = dec_out @ w_proj^T + b_proj
  k_gemm<0><<<dim3(250, 16), 256, 0, stream>>>(dOutB, Wp, b_proj, nullptr, out, 2048, 32000, 1024);
}